// Round 1
// baseline (348.375 us; speedup 1.0000x reference)
//
#include <hip/hip_runtime.h>
#include <math.h>

#pragma clang fp contract(off)

#define BS 16
#define NA 8400
#define NG 128
#define NC 80
#define KTOP 13

// ---- workspace layout (bytes) ----
#define ALIGN_BYTES ((size_t)BS * NG * NA * 4)            // 68,812,800
#define BITS_BYTES  ((size_t)BS * NA * 4 * 4)             //  2,150,400
#define OFF_BITS    (ALIGN_BYTES)
#define OFF_FLAG    (OFF_BITS + BITS_BYTES)
#define OFF_TOPIDX  (OFF_FLAG + 256)

// ---- output layout (float elements) ----
#define OUT_CLS    0
#define OUT_BBOX   (BS * NA)                               // 134,400
#define OUT_SCORES (OUT_BBOX + BS * NA * 4)                // 672,000
#define OUT_MASK   (OUT_SCORES + BS * NA * NC)             // 11,424,000
#define OUT_NORM   (OUT_MASK + BS * NA)                    // 11,558,400

__device__ __forceinline__ float dev_ciou(float px1, float py1, float px2, float py2,
                                          float gx1, float gy1, float gx2, float gy2) {
    const float eps = 1e-7f;
    float iw = fminf(px2, gx2) - fmaxf(px1, gx1); iw = fmaxf(iw, 0.0f);
    float ih = fminf(py2, gy2) - fmaxf(py1, gy1); ih = fmaxf(ih, 0.0f);
    float inter = iw * ih;
    float w1 = px2 - px1;
    float h1 = (py2 - py1) + eps;
    float w2 = gx2 - gx1;
    float h2 = (gy2 - gy1) + eps;
    float uni = ((w1 * h1 + w2 * h2) - inter) + eps;
    float iou = inter / uni;
    float cw = fmaxf(px2, gx2) - fminf(px1, gx1);
    float ch = fmaxf(py2, gy2) - fminf(py1, gy1);
    float c2 = (cw * cw + ch * ch) + eps;
    float tx = ((gx1 + gx2) - px1) - px2;
    float ty = ((gy1 + gy2) - py1) - py2;
    float rho2 = (tx * tx + ty * ty) / 4.0f;
    float da = atanf(w2 / h2) - atanf(w1 / h1);
    float v = ((float)(4.0 / (M_PI * M_PI))) * (da * da);
    float alpha = v / ((v - iou) + (float)(1.0 + 1e-7));
    float res = iou - (rho2 / c2 + v * alpha);
    return fmaxf(res, 0.0f);
}

// K1: align[b][g][a] = score^1 * ciou^6 * mask_in_gts * gt_mask
__global__ __launch_bounds__(256) void k_align(
    const float* __restrict__ scores, const float* __restrict__ pboxes,
    const float* __restrict__ anc, const int* __restrict__ glab,
    const float* __restrict__ gboxes, const float* __restrict__ gmask,
    float* __restrict__ alignM)
{
    int a = blockIdx.x * 256 + threadIdx.x;
    int g = blockIdx.y;
    int b = blockIdx.z;
    if (a >= NA) return;
    int bg = b * NG + g;
    float gx1 = gboxes[bg * 4 + 0], gy1 = gboxes[bg * 4 + 1];
    float gx2 = gboxes[bg * 4 + 2], gy2 = gboxes[bg * 4 + 3];
    float ax = anc[a * 2 + 0], ay = anc[a * 2 + 1];
    float mn = fminf(fminf(ax - gx1, ay - gy1), fminf(gx2 - ax, gy2 - ay));
    float gm = gmask[bg];
    size_t oidx = (size_t)bg * NA + a;
    if (!(mn > 1e-9f) || !(gm != 0.0f)) {   // mask_pos == 0 -> align exactly 0
        // note: if mn<=eps, mask=0 regardless of gm; if gm==0, mask=0 too.
        // reference: maskp = in_gt ? gm : 0 ; align = x*maskp. gm is 1.0 here.
        float maskp = (mn > 1e-9f) ? gm : 0.0f;
        if (maskp == 0.0f) { alignM[oidx] = 0.0f; return; }
    }
    float maskp = (mn > 1e-9f) ? gm : 0.0f;
    size_t pa = (size_t)b * NA + a;
    float px1 = pboxes[pa * 4 + 0], py1 = pboxes[pa * 4 + 1];
    float px2 = pboxes[pa * 4 + 2], py2 = pboxes[pa * 4 + 3];
    float iou = dev_ciou(px1, py1, px2, py2, gx1, gy1, gx2, gy2);
    int cls = glab[bg];
    float s = scores[pa * NC + cls];
    float al = (s * powf(iou, 6.0f)) * maskp;
    alignM[oidx] = al;
}

// K2: top-13 per (b,g) column, value-desc / index-asc tiebreak (jax.lax.top_k)
__global__ __launch_bounds__(256) void k_topk(const float* __restrict__ alignM,
                                              int* __restrict__ topidx)
{
    __shared__ float vals[NA];
    __shared__ float rv[4];
    __shared__ int ri[4];
    int g = blockIdx.x;
    int b = blockIdx.y;
    const float* col = alignM + ((size_t)(b * NG) + g) * NA;
    for (int i = threadIdx.x; i < NA; i += 256) vals[i] = col[i];
    __syncthreads();
    for (int k = 0; k < KTOP; k++) {
        float bv = -1.0f; int bi = NA;
        for (int i = threadIdx.x; i < NA; i += 256) {
            float v = vals[i];
            if (v > bv || (v == bv && i < bi)) { bv = v; bi = i; }
        }
        for (int off = 32; off > 0; off >>= 1) {
            float ov = __shfl_down(bv, off);
            int   oi = __shfl_down(bi, off);
            if (ov > bv || (ov == bv && oi < bi)) { bv = ov; bi = oi; }
        }
        int wid = threadIdx.x >> 6;
        if ((threadIdx.x & 63) == 0) { rv[wid] = bv; ri[wid] = bi; }
        __syncthreads();
        if (threadIdx.x == 0) {
            for (int w = 1; w < 4; w++) {
                if (rv[w] > bv || (rv[w] == bv && ri[w] < bi)) { bv = rv[w]; bi = ri[w]; }
            }
            topidx[(b * NG + g) * KTOP + k] = bi;
            vals[bi] = -1.0f;   // remove; align >= 0 so -1 never re-selected over real
        }
        __syncthreads();
    }
}

// K3: scatter top-k indices into per-anchor 128-bit gt masks (gt_mask>0 applied here)
__global__ void k_scatter(const int* __restrict__ topidx, const float* __restrict__ gmask,
                          unsigned int* __restrict__ bits)
{
    int i = blockIdx.x * blockDim.x + threadIdx.x;
    if (i >= BS * NG * KTOP) return;
    int bg = i / KTOP;
    int g = bg % NG;
    int b = bg / NG;
    if (gmask[bg] > 0.0f) {
        int a = topidx[i];
        atomicOr(&bits[((size_t)b * NA + a) * 4 + (g >> 5)], 1u << (g & 31));
    }
}

// K4: global conflict.any() flag (effective is_in count > 1 for any anchor)
__global__ __launch_bounds__(256) void k_conflict(const unsigned int* __restrict__ bits,
                                                  const float* __restrict__ alignM,
                                                  int* __restrict__ flag)
{
    int t = blockIdx.x * 256 + threadIdx.x;   // t in [0, BS*NA), exact multiple of 256
    int b = t / NA, a = t % NA;
    const float* col = alignM + (size_t)b * NG * NA + a;
    int cnt = 0;
    for (int w = 0; w < 4; w++) {
        unsigned int m = bits[(size_t)t * 4 + w];
        while (m) {
            int j = __ffs(m) - 1; m &= m - 1;
            int g = w * 32 + j;
            if (col[(size_t)g * NA] > 1e-9f) cnt++;
        }
    }
    if (__any(cnt > 1)) {
        if ((threadIdx.x & 63) == 0) atomicOr(flag, 1);
    }
}

// K5: per-anchor resolution + all 5 outputs
__global__ __launch_bounds__(256) void k_final(
    const float* __restrict__ alignM, const unsigned int* __restrict__ bits,
    const int* __restrict__ flagp, const float* __restrict__ pboxes,
    const int* __restrict__ glab, const float* __restrict__ gboxes,
    float* __restrict__ o_cls, float* __restrict__ o_bbox, float* __restrict__ o_scores,
    float* __restrict__ o_mask, float* __restrict__ o_norm)
{
    __shared__ float s_gb[NG * 4];
    __shared__ int s_gl[NG];
    int b = blockIdx.y;
    for (int i = threadIdx.x; i < NG * 4; i += 256) s_gb[i] = gboxes[b * NG * 4 + i];
    for (int i = threadIdx.x; i < NG; i += 256) s_gl[i] = glab[b * NG + i];
    __syncthreads();
    int a = blockIdx.x * 256 + threadIdx.x;
    if (a >= NA) return;
    size_t t = (size_t)b * NA + a;
    unsigned int mw0 = bits[t * 4 + 0], mw1 = bits[t * 4 + 1];
    unsigned int mw2 = bits[t * 4 + 2], mw3 = bits[t * 4 + 3];
    bool conflict_any = (flagp[0] != 0);
    float px1 = pboxes[t * 4 + 0], py1 = pboxes[t * 4 + 1];
    float px2 = pboxes[t * 4 + 2], py2 = pboxes[t * 4 + 3];
    const float* col = alignM + (size_t)b * NG * NA + a;

    // pass over all g: argmax(align) (first occurrence) + effective is_in bits
    unsigned int ew[4] = {0u, 0u, 0u, 0u};
    unsigned int mwall[4] = {mw0, mw1, mw2, mw3};
    float best_v = -1.0f; int best_g = 0; int cnt = 0;
    for (int w = 0; w < 4; w++) {
        unsigned int m = mwall[w];
        for (int j = 0; j < 32; j++) {
            int g = w * 32 + j;
            float v = col[(size_t)g * NA];
            if (v > best_v) { best_v = v; best_g = g; }
            if (((m >> j) & 1u) && v > 1e-9f) { ew[w] |= (1u << j); cnt++; }
        }
    }

    bool keep = (cnt <= 1);
    float M = 0.0f, mxiou = 0.0f;
    int tgt = 0;
    float fmask = 0.0f;

    if (!conflict_any) {
        fmask = (cnt > 0) ? 1.0f : 0.0f;
        for (int w = 0; w < 4; w++) {
            if (ew[w]) { tgt = w * 32 + __ffs(ew[w]) - 1; break; }
        }
        for (int w = 0; w < 4; w++) {
            unsigned int m = ew[w];
            while (m) {
                int j = __ffs(m) - 1; m &= m - 1;
                int g = w * 32 + j;
                float av = col[(size_t)g * NA];
                float iv = dev_ciou(px1, py1, px2, py2,
                                    s_gb[g * 4 + 0], s_gb[g * 4 + 1], s_gb[g * 4 + 2], s_gb[g * 4 + 3]);
                M = fmaxf(M, av);
                mxiou = fmaxf(mxiou, iv);
            }
        }
    } else if (!keep) {
        fmask = 0.0f; tgt = 0; M = 0.0f; mxiou = 0.0f;   // resolved row is all zero
    } else {
        fmask = 1.0f;   // one_hot_best always contributes 1
        bool eff_best = ((ew[best_g >> 5] >> (best_g & 31)) & 1u) != 0u;
        int first_eff = 1 << 30;
        for (int w = 0; w < 4; w++) {
            if (ew[w]) { first_eff = w * 32 + __ffs(ew[w]) - 1; break; }
        }
        tgt = eff_best ? best_g : (first_eff < best_g ? first_eff : best_g);
        for (int w = 0; w < 4; w++) {
            unsigned int m = ew[w];
            while (m) {
                int j = __ffs(m) - 1; m &= m - 1;
                int g = w * 32 + j;
                float r = (g == best_g) ? 2.0f : 1.0f;
                float av = col[(size_t)g * NA];
                float iv = dev_ciou(px1, py1, px2, py2,
                                    s_gb[g * 4 + 0], s_gb[g * 4 + 1], s_gb[g * 4 + 2], s_gb[g * 4 + 3]);
                M = fmaxf(M, av * r);
                mxiou = fmaxf(mxiou, iv * r);
            }
        }
        if (!eff_best) {   // one_hot_best adds r=1 at best_g (even if align there is 0)
            float iv = dev_ciou(px1, py1, px2, py2,
                                s_gb[best_g * 4 + 0], s_gb[best_g * 4 + 1],
                                s_gb[best_g * 4 + 2], s_gb[best_g * 4 + 3]);
            M = fmaxf(M, best_v);
            mxiou = fmaxf(mxiou, iv);
        }
    }

    float norm = (M * M) / (mxiou + 1e-9f);
    int cls = s_gl[tgt];
    o_cls[t] = (float)cls;
    o_bbox[t * 4 + 0] = s_gb[tgt * 4 + 0];
    o_bbox[t * 4 + 1] = s_gb[tgt * 4 + 1];
    o_bbox[t * 4 + 2] = s_gb[tgt * 4 + 2];
    o_bbox[t * 4 + 3] = s_gb[tgt * 4 + 3];
    o_mask[t] = fmask;
    o_norm[t] = norm;
    o_scores[t * (size_t)NC + cls] = norm;   // rest of row pre-zeroed by memset
}

extern "C" void kernel_launch(void* const* d_in, const int* in_sizes, int n_in,
                              void* d_out, int out_size, void* d_ws, size_t ws_size,
                              hipStream_t stream) {
    const float* pd_scores = (const float*)d_in[0];
    const float* pd_bboxes = (const float*)d_in[1];
    const float* anc       = (const float*)d_in[2];
    const int*   glab      = (const int*)d_in[3];
    const float* gboxes    = (const float*)d_in[4];
    const float* gmask     = (const float*)d_in[5];
    float* out = (float*)d_out;

    char* ws = (char*)d_ws;
    float*        alignM = (float*)ws;
    unsigned int* bits   = (unsigned int*)(ws + OFF_BITS);
    int*          flag   = (int*)(ws + OFF_FLAG);
    int*          topidx = (int*)(ws + OFF_TOPIDX);

    // zero the bitmask + flag (ws is poisoned 0xAA each call) and the output buffer
    hipMemsetAsync(bits, 0, BITS_BYTES + 4, stream);
    hipMemsetAsync(d_out, 0, (size_t)out_size * sizeof(float), stream);

    k_align<<<dim3((NA + 255) / 256, NG, BS), 256, 0, stream>>>(
        pd_scores, pd_bboxes, anc, glab, gboxes, gmask, alignM);

    k_topk<<<dim3(NG, BS), 256, 0, stream>>>(alignM, topidx);

    k_scatter<<<(BS * NG * KTOP + 255) / 256, 256, 0, stream>>>(topidx, gmask, bits);

    k_conflict<<<(BS * NA) / 256, 256, 0, stream>>>(bits, alignM, flag);

    k_final<<<dim3((NA + 255) / 256, BS), 256, 0, stream>>>(
        alignM, bits, flag, pd_bboxes, glab, gboxes,
        out + OUT_CLS, out + OUT_BBOX, out + OUT_SCORES, out + OUT_MASK, out + OUT_NORM);
}

// Round 2
// 251.422 us; speedup vs baseline: 1.3856x; 1.3856x over previous
//
#include <hip/hip_runtime.h>
#include <math.h>

#pragma clang fp contract(off)

#define BS 16
#define NA 8400
#define NG 128
#define NC 80
#define KTOP 13
#define CAP 1024   // per-column compacted-list capacity (worst case ~500)

// ---- workspace layout (bytes) ----
#define OFF_COUNTS 0                                   // 2048 * 4        = 8192
#define OFF_BITS   (OFF_COUNTS + BS * NG * 4)          // BS*NA*4 words   = 2,150,400
#define OFF_SELCNT (OFF_BITS + (size_t)BS * NA * 16)   // BS*NA * 4       =   537,600
#define OFF_FLAG   (OFF_SELCNT + (size_t)BS * NA * 4)  // 256 (flag slot)
#define ZERO_END   (OFF_FLAG + 256)
#define OFF_PAIRS  ZERO_END                            // 2048*CAP*8      = 16,777,216
#define OFF_BESTV  (OFF_PAIRS + (size_t)BS * NG * CAP * 8)
#define OFF_BESTG  (OFF_BESTV + (size_t)BS * NA * 4)

// ---- output layout (float elements) ----
#define OUT_CLS    0
#define OUT_BBOX   (BS * NA)
#define OUT_SCORES (OUT_BBOX + BS * NA * 4)
#define OUT_MASK   (OUT_SCORES + BS * NA * NC)
#define OUT_NORM   (OUT_MASK + BS * NA)

__device__ __forceinline__ float dev_ciou(float px1, float py1, float px2, float py2,
                                          float gx1, float gy1, float gx2, float gy2) {
    const float eps = 1e-7f;
    float iw = fminf(px2, gx2) - fmaxf(px1, gx1); iw = fmaxf(iw, 0.0f);
    float ih = fminf(py2, gy2) - fmaxf(py1, gy1); ih = fmaxf(ih, 0.0f);
    float inter = iw * ih;
    float w1 = px2 - px1;
    float h1 = (py2 - py1) + eps;
    float w2 = gx2 - gx1;
    float h2 = (gy2 - gy1) + eps;
    float uni = ((w1 * h1 + w2 * h2) - inter) + eps;
    float iou = inter / uni;
    float cw = fmaxf(px2, gx2) - fminf(px1, gx1);
    float ch = fmaxf(py2, gy2) - fminf(py1, gy1);
    float c2 = (cw * cw + ch * ch) + eps;
    float tx = ((gx1 + gx2) - px1) - px2;
    float ty = ((gy1 + gy2) - py1) - py2;
    float rho2 = (tx * tx + ty * ty) / 4.0f;
    float da = atanf(w2 / h2) - atanf(w1 / h1);
    float v = ((float)(4.0 / (M_PI * M_PI))) * (da * da);
    float alpha = v / ((v - iou) + (float)(1.0 + 1e-7));
    float res = iou - (rho2 / c2 + v * alpha);
    return fmaxf(res, 0.0f);
}

// K1: per (b,anchor) thread. Loop all 128 gts: cheap in-box mask; for in-box gts
// compute align, append (val,anchor) to per-column list if >1e-9, track row argmax.
__global__ __launch_bounds__(256) void k_build(
    const float* __restrict__ scores, const float* __restrict__ pboxes,
    const float* __restrict__ anc, const int* __restrict__ glab,
    const float* __restrict__ gboxes, const float* __restrict__ gmask,
    unsigned int* __restrict__ counts, uint2* __restrict__ pairs,
    float* __restrict__ bestv, int* __restrict__ bestg)
{
    __shared__ float4 s_gb[NG];
    __shared__ int s_gl[NG];
    __shared__ float s_gm[NG];
    int b = blockIdx.y;
    for (int i = threadIdx.x; i < NG; i += 256) {
        s_gb[i] = ((const float4*)gboxes)[b * NG + i];
        s_gl[i] = glab[b * NG + i];
        s_gm[i] = gmask[b * NG + i];
    }
    __syncthreads();
    int a = blockIdx.x * 256 + threadIdx.x;
    if (a >= NA) return;
    size_t t = (size_t)b * NA + a;
    float ax = anc[a * 2 + 0], ay = anc[a * 2 + 1];
    float4 pb = ((const float4*)pboxes)[t];
    const float* srow = scores + t * NC;
    float best_v = -1.0f; int best_g = 0;
    for (int g = 0; g < NG; g++) {
        float4 gb = s_gb[g];
        float mn = fminf(fminf(ax - gb.x, ay - gb.y), fminf(gb.z - ax, gb.w - ay));
        float gm = s_gm[g];
        float maskp = (mn > 1e-9f) ? gm : 0.0f;
        float al = 0.0f;
        if (maskp != 0.0f) {
            float iou = dev_ciou(pb.x, pb.y, pb.z, pb.w, gb.x, gb.y, gb.z, gb.w);
            float s = srow[s_gl[g]];
            al = (s * powf(iou, 6.0f)) * maskp;
            if (al > 1e-9f) {
                int col = b * NG + g;
                unsigned int pos = atomicAdd(&counts[col], 1u);
                if (pos < CAP)
                    pairs[(size_t)col * CAP + pos] = make_uint2(__float_as_uint(al), (unsigned int)a);
            }
        }
        if (al > best_v) { best_v = al; best_g = g; }   // first-occurrence argmax
    }
    bestv[t] = best_v;
    bestg[t] = best_g;
}

// K2: one wave per column. Top-13 over the compacted list (value desc, anchor asc
// tiebreak = jax.lax.top_k). Scatter bits + fused conflict.any() flag via selcnt.
__global__ __launch_bounds__(256) void k_select(
    const unsigned int* __restrict__ counts, const uint2* __restrict__ pairs,
    const float* __restrict__ gmask,
    unsigned int* __restrict__ bits, unsigned int* __restrict__ selcnt,
    int* __restrict__ flag)
{
    int col = blockIdx.x * 4 + (threadIdx.x >> 6);
    int lane = threadIdx.x & 63;
    if (col >= BS * NG) return;
    if (!(gmask[col] > 0.0f)) return;
    int b = col >> 7, g = col & 127;
    int cnt = (int)counts[col]; if (cnt > CAP) cnt = CAP;
    float v[CAP / 64];
    unsigned int ai[CAP / 64];
    #pragma unroll
    for (int j = 0; j < CAP / 64; j++) {
        int i = lane + j * 64;
        if (i < cnt) {
            uint2 p = pairs[(size_t)col * CAP + i];
            v[j] = __uint_as_float(p.x); ai[j] = p.y;
        } else { v[j] = -1.0f; ai[j] = 0xFFFFFFFFu; }
    }
    int nk = cnt < KTOP ? cnt : KTOP;
    for (int k = 0; k < nk; k++) {
        float bv = -1.0f; unsigned int ba = 0xFFFFFFFFu;
        #pragma unroll
        for (int j = 0; j < CAP / 64; j++) {
            if (v[j] > bv || (v[j] == bv && ai[j] < ba)) { bv = v[j]; ba = ai[j]; }
        }
        for (int off = 1; off < 64; off <<= 1) {
            float ov = __shfl_xor(bv, off);
            unsigned int oa = (unsigned int)__shfl_xor((int)ba, off);
            if (ov > bv || (ov == bv && oa < ba)) { bv = ov; ba = oa; }
        }
        #pragma unroll
        for (int j = 0; j < CAP / 64; j++) {
            if (ai[j] == ba) v[j] = -1.0f;   // anchors unique within a column
        }
        if (lane == 0) {
            size_t t = (size_t)b * NA + ba;
            atomicOr(&bits[t * 4 + (g >> 5)], 1u << (g & 31));
            unsigned int old = atomicAdd(&selcnt[t], 1u);
            if (old >= 1u) atomicOr(flag, 1);
        }
    }
}

// K3: per-anchor resolution + all 5 outputs (align/iou recomputed only at set bits)
__global__ __launch_bounds__(256) void k_final(
    const float* __restrict__ scores, const float* __restrict__ pboxes,
    const int* __restrict__ glab, const float* __restrict__ gboxes,
    const float* __restrict__ gmask,
    const unsigned int* __restrict__ bits, const int* __restrict__ flagp,
    const float* __restrict__ bestvp, const int* __restrict__ bestgp,
    float* __restrict__ o_cls, float* __restrict__ o_bbox, float* __restrict__ o_scores,
    float* __restrict__ o_mask, float* __restrict__ o_norm)
{
    __shared__ float4 s_gb[NG];
    __shared__ int s_gl[NG];
    __shared__ float s_gm[NG];
    int b = blockIdx.y;
    for (int i = threadIdx.x; i < NG; i += 256) {
        s_gb[i] = ((const float4*)gboxes)[b * NG + i];
        s_gl[i] = glab[b * NG + i];
        s_gm[i] = gmask[b * NG + i];
    }
    __syncthreads();
    int a = blockIdx.x * 256 + threadIdx.x;
    if (a >= NA) return;
    size_t t = (size_t)b * NA + a;
    unsigned int ew[4];
    ew[0] = bits[t * 4 + 0]; ew[1] = bits[t * 4 + 1];
    ew[2] = bits[t * 4 + 2]; ew[3] = bits[t * 4 + 3];
    int cnt = __popc(ew[0]) + __popc(ew[1]) + __popc(ew[2]) + __popc(ew[3]);
    bool conflict_any = (flagp[0] != 0);
    float best_v = bestvp[t]; int best_g = bestgp[t];
    float4 pb = ((const float4*)pboxes)[t];
    const float* srow = scores + t * NC;

    bool keep = (cnt <= 1);
    float M = 0.0f, mxiou = 0.0f;
    int tgt = 0;
    float fmask = 0.0f;

    if (!conflict_any) {
        fmask = (cnt > 0) ? 1.0f : 0.0f;
        for (int w = 0; w < 4; w++) {
            if (ew[w]) { tgt = w * 32 + __ffs(ew[w]) - 1; break; }
        }
        for (int w = 0; w < 4; w++) {
            unsigned int m = ew[w];
            while (m) {
                int j = __ffs(m) - 1; m &= m - 1;
                int g = w * 32 + j;
                float4 gb = s_gb[g];
                float iv = dev_ciou(pb.x, pb.y, pb.z, pb.w, gb.x, gb.y, gb.z, gb.w);
                float s = srow[s_gl[g]];
                float av = (s * powf(iv, 6.0f)) * s_gm[g];   // bit-identical to k_build
                M = fmaxf(M, av);
                mxiou = fmaxf(mxiou, iv);
            }
        }
    } else if (!keep) {
        fmask = 0.0f; tgt = 0; M = 0.0f; mxiou = 0.0f;   // resolved row all zero
    } else {
        fmask = 1.0f;   // one_hot_best always contributes
        bool eff_best = ((ew[best_g >> 5] >> (best_g & 31)) & 1u) != 0u;
        int first_eff = 1 << 30;
        for (int w = 0; w < 4; w++) {
            if (ew[w]) { first_eff = w * 32 + __ffs(ew[w]) - 1; break; }
        }
        tgt = eff_best ? best_g : (first_eff < best_g ? first_eff : best_g);
        for (int w = 0; w < 4; w++) {
            unsigned int m = ew[w];
            while (m) {
                int j = __ffs(m) - 1; m &= m - 1;
                int g = w * 32 + j;
                float r = (g == best_g) ? 2.0f : 1.0f;
                float4 gb = s_gb[g];
                float iv = dev_ciou(pb.x, pb.y, pb.z, pb.w, gb.x, gb.y, gb.z, gb.w);
                float s = srow[s_gl[g]];
                float av = (s * powf(iv, 6.0f)) * s_gm[g];
                M = fmaxf(M, av * r);
                mxiou = fmaxf(mxiou, iv * r);
            }
        }
        if (!eff_best) {   // one_hot_best adds weight 1 at best_g (iou there counts too)
            float4 gb = s_gb[best_g];
            float iv = dev_ciou(pb.x, pb.y, pb.z, pb.w, gb.x, gb.y, gb.z, gb.w);
            M = fmaxf(M, best_v);
            mxiou = fmaxf(mxiou, iv);
        }
    }

    float norm = (M * M) / (mxiou + 1e-9f);
    int cls = s_gl[tgt];
    float4 gb = s_gb[tgt];
    o_cls[t] = (float)cls;
    ((float4*)o_bbox)[t] = gb;
    o_mask[t] = fmask;
    o_norm[t] = norm;
    // full one-hot score row (replaces the 43 MB memset)
    float* orow = o_scores + t * (size_t)NC;
    #pragma unroll
    for (int j = 0; j < NC / 4; j++) {
        int base = j * 4;
        float4 z;
        z.x = (cls == base + 0) ? norm : 0.0f;
        z.y = (cls == base + 1) ? norm : 0.0f;
        z.z = (cls == base + 2) ? norm : 0.0f;
        z.w = (cls == base + 3) ? norm : 0.0f;
        ((float4*)orow)[j] = z;
    }
}

extern "C" void kernel_launch(void* const* d_in, const int* in_sizes, int n_in,
                              void* d_out, int out_size, void* d_ws, size_t ws_size,
                              hipStream_t stream) {
    const float* pd_scores = (const float*)d_in[0];
    const float* pd_bboxes = (const float*)d_in[1];
    const float* anc       = (const float*)d_in[2];
    const int*   glab      = (const int*)d_in[3];
    const float* gboxes    = (const float*)d_in[4];
    const float* gmask     = (const float*)d_in[5];
    float* out = (float*)d_out;

    char* ws = (char*)d_ws;
    unsigned int* counts = (unsigned int*)(ws + OFF_COUNTS);
    unsigned int* bits   = (unsigned int*)(ws + OFF_BITS);
    unsigned int* selcnt = (unsigned int*)(ws + OFF_SELCNT);
    int*          flag   = (int*)(ws + OFF_FLAG);
    uint2*        pairs  = (uint2*)(ws + OFF_PAIRS);
    float*        bestv  = (float*)(ws + OFF_BESTV);
    int*          bestg  = (int*)(ws + OFF_BESTG);

    hipMemsetAsync(ws, 0, ZERO_END, stream);

    k_build<<<dim3((NA + 255) / 256, BS), 256, 0, stream>>>(
        pd_scores, pd_bboxes, anc, glab, gboxes, gmask, counts, pairs, bestv, bestg);

    k_select<<<dim3(BS * NG / 4), 256, 0, stream>>>(
        counts, pairs, gmask, bits, selcnt, flag);

    k_final<<<dim3((NA + 255) / 256, BS), 256, 0, stream>>>(
        pd_scores, pd_bboxes, glab, gboxes, gmask, bits, flag, bestv, bestg,
        out + OUT_CLS, out + OUT_BBOX, out + OUT_SCORES, out + OUT_MASK, out + OUT_NORM);
}

// Round 3
// 139.424 us; speedup vs baseline: 2.4987x; 1.8033x over previous
//
#include <hip/hip_runtime.h>
#include <math.h>

#pragma clang fp contract(off)

#define BS 16
#define NA 8400
#define NG 128
#define NC 80
#define KTOP 13
#define CAP 1024   // per-column compacted-list capacity (worst case ~500)

// ---- workspace layout (bytes) ----
#define OFF_COUNTS 0                                   // 2048 * 4        = 8192
#define OFF_BITS   (OFF_COUNTS + BS * NG * 4)          // BS*NA*4 words   = 2,150,400
#define OFF_SELCNT (OFF_BITS + (size_t)BS * NA * 16)   // BS*NA * 4       =   537,600
#define OFF_FLAG   (OFF_SELCNT + (size_t)BS * NA * 4)  // 256 (flag slot)
#define ZERO_END   (OFF_FLAG + 256)
#define OFF_PAIRS  ZERO_END                            // 2048*CAP*8      = 16,777,216
#define OFF_BESTV  (OFF_PAIRS + (size_t)BS * NG * CAP * 8)
#define OFF_BESTG  (OFF_BESTV + (size_t)BS * NA * 4)

// ---- output layout (float elements) ----
#define OUT_CLS    0
#define OUT_BBOX   (BS * NA)
#define OUT_SCORES (OUT_BBOX + BS * NA * 4)
#define OUT_MASK   (OUT_SCORES + BS * NA * NC)
#define OUT_NORM   (OUT_MASK + BS * NA)

__device__ __forceinline__ float dev_ciou(float px1, float py1, float px2, float py2,
                                          float gx1, float gy1, float gx2, float gy2) {
    const float eps = 1e-7f;
    float iw = fminf(px2, gx2) - fmaxf(px1, gx1); iw = fmaxf(iw, 0.0f);
    float ih = fminf(py2, gy2) - fmaxf(py1, gy1); ih = fmaxf(ih, 0.0f);
    float inter = iw * ih;
    float w1 = px2 - px1;
    float h1 = (py2 - py1) + eps;
    float w2 = gx2 - gx1;
    float h2 = (gy2 - gy1) + eps;
    float uni = ((w1 * h1 + w2 * h2) - inter) + eps;
    float iou = inter / uni;
    float cw = fmaxf(px2, gx2) - fminf(px1, gx1);
    float ch = fmaxf(py2, gy2) - fminf(py1, gy1);
    float c2 = (cw * cw + ch * ch) + eps;
    float tx = ((gx1 + gx2) - px1) - px2;
    float ty = ((gy1 + gy2) - py1) - py2;
    float rho2 = (tx * tx + ty * ty) / 4.0f;
    float da = atanf(w2 / h2) - atanf(w1 / h1);
    float v = ((float)(4.0 / (M_PI * M_PI))) * (da * da);
    float alpha = v / ((v - iou) + (float)(1.0 + 1e-7));
    float res = iou - (rho2 / c2 + v * alpha);
    return fmaxf(res, 0.0f);
}

// K1: compact-then-compute. Block = 64 anchors x 4 g-chunks (4 waves).
// Phase 1: cheap in-box tests -> LDS queue of (a_local,g). Phase 2: dense
// drain of the queue: ciou+powf at ~full lane utilization; per-anchor argmax
// via packed LDS atomicMax; append (al,anchor) to per-column global lists.
__global__ __launch_bounds__(256) void k_build(
    const float* __restrict__ scores, const float* __restrict__ pboxes,
    const float* __restrict__ anc, const int* __restrict__ glab,
    const float* __restrict__ gboxes, const float* __restrict__ gmask,
    unsigned int* __restrict__ counts, uint2* __restrict__ pairs,
    float* __restrict__ bestv, int* __restrict__ bestg)
{
    __shared__ float4 s_gb[NG];
    __shared__ int s_gl[NG];
    __shared__ float s_gm[NG];
    __shared__ unsigned long long s_best[64];
    __shared__ unsigned short s_q[64 * NG];   // worst case: every cell in-box
    __shared__ unsigned int s_qn;
    int b = blockIdx.y;
    int tid = threadIdx.x;
    if (tid == 0) s_qn = 0;
    for (int i = tid; i < NG; i += 256) {
        s_gb[i] = ((const float4*)gboxes)[b * NG + i];
        s_gl[i] = glab[b * NG + i];
        s_gm[i] = gmask[b * NG + i];
    }
    if (tid < 64) s_best[tid] = 127ULL;   // pack(al=0.0f, g=0) = (0<<32)|(127-0)
    __syncthreads();

    int lane = tid & 63;
    int chunk = tid >> 6;
    int a0 = blockIdx.x * 64;
    int a = a0 + lane;
    bool valid = (a < NA);
    float ax = -1e30f, ay = -1e30f;
    if (valid) { ax = anc[a * 2 + 0]; ay = anc[a * 2 + 1]; }

    // phase 1: cheap mask, push hits
    for (int j = 0; j < 32; j++) {
        int g = chunk * 32 + j;
        float4 gb = s_gb[g];
        float mn = fminf(fminf(ax - gb.x, ay - gb.y), fminf(gb.z - ax, gb.w - ay));
        if (valid && mn > 1e-9f && s_gm[g] != 0.0f) {
            unsigned int pos = atomicAdd(&s_qn, 1u);
            s_q[pos] = (unsigned short)((lane << 7) | g);
        }
    }
    __syncthreads();

    // phase 2: dense expensive pass over the queue
    int qn = (int)s_qn;
    for (int i = tid; i < qn; i += 256) {
        int e = (int)s_q[i];
        int al_ = e >> 7, g = e & 127;
        int aa = a0 + al_;
        size_t t = (size_t)b * NA + aa;
        float4 gb = s_gb[g];
        float4 pb = ((const float4*)pboxes)[t];
        float iou = dev_ciou(pb.x, pb.y, pb.z, pb.w, gb.x, gb.y, gb.z, gb.w);
        float s = scores[t * NC + s_gl[g]];
        float al = (s * powf(iou, 6.0f)) * s_gm[g];   // same expr as reference path
        if (al > 1e-9f) {
            int col = b * NG + g;
            unsigned int pos = atomicAdd(&counts[col], 1u);
            if (pos < CAP)
                pairs[(size_t)col * CAP + pos] = make_uint2(__float_as_uint(al), (unsigned int)aa);
        }
        // first-occurrence argmax: al>=0 so float bits are order-monotone;
        // low 7 bits (127-g) make smaller g win ties under max.
        unsigned long long key =
            ((unsigned long long)__float_as_uint(al) << 32) | (unsigned int)(127 - g);
        atomicMax(&s_best[al_], key);
    }
    __syncthreads();

    // phase 3: write per-anchor best
    if (tid < 64 && a0 + tid < NA) {
        unsigned long long key = s_best[tid];
        size_t t = (size_t)b * NA + a0 + tid;
        bestv[t] = __uint_as_float((unsigned int)(key >> 32));
        bestg[t] = 127 - (int)(key & 0x7Fu);
    }
}

// K2: one wave per column. Top-13 over the compacted list in LDS (dynamic
// chunk count). Value desc, anchor-index asc tiebreak = jax.lax.top_k.
__global__ __launch_bounds__(256) void k_select(
    const unsigned int* __restrict__ counts, const uint2* __restrict__ pairs,
    const float* __restrict__ gmask,
    unsigned int* __restrict__ bits, unsigned int* __restrict__ selcnt,
    int* __restrict__ flag)
{
    __shared__ uint2 s_list[4][CAP];
    int wv = threadIdx.x >> 6, lane = threadIdx.x & 63;
    int col = blockIdx.x * 4 + wv;
    if (col >= BS * NG) return;
    if (!(gmask[col] > 0.0f)) return;
    int b = col >> 7, g = col & 127;
    int cnt = (int)counts[col]; if (cnt > CAP) cnt = CAP;
    uint2* lst = s_list[wv];
    for (int i = lane; i < cnt; i += 64) lst[i] = pairs[(size_t)col * CAP + i];
    int nch = (cnt + 63) >> 6;
    int nk = cnt < KTOP ? cnt : KTOP;
    for (int k = 0; k < nk; k++) {
        float bv = -1.0f; unsigned int ba = 0xFFFFFFFFu;
        for (int j = 0; j < nch; j++) {
            int i = lane + j * 64;
            if (i < cnt) {
                uint2 p = lst[i];
                float v = __uint_as_float(p.x);
                if (v > bv || (v == bv && p.y < ba)) { bv = v; ba = p.y; }
            }
        }
        for (int off = 1; off < 64; off <<= 1) {
            float ov = __shfl_xor(bv, off);
            unsigned int oa = (unsigned int)__shfl_xor((int)ba, off);
            if (ov > bv || (ov == bv && oa < ba)) { bv = ov; ba = oa; }
        }
        for (int j = 0; j < nch; j++) {
            int i = lane + j * 64;
            if (i < cnt && lst[i].y == ba) lst[i].x = __float_as_uint(-1.0f);
        }
        if (lane == 0) {
            size_t t = (size_t)b * NA + ba;
            atomicOr(&bits[t * 4 + (g >> 5)], 1u << (g & 31));
            unsigned int old = atomicAdd(&selcnt[t], 1u);
            if (old >= 1u) atomicOr(flag, 1);
        }
    }
}

// K3: per-anchor resolution + all 5 outputs (align/iou recomputed only at set bits)
__global__ __launch_bounds__(256) void k_final(
    const float* __restrict__ scores, const float* __restrict__ pboxes,
    const int* __restrict__ glab, const float* __restrict__ gboxes,
    const float* __restrict__ gmask,
    const unsigned int* __restrict__ bits, const int* __restrict__ flagp,
    const float* __restrict__ bestvp, const int* __restrict__ bestgp,
    float* __restrict__ o_cls, float* __restrict__ o_bbox, float* __restrict__ o_scores,
    float* __restrict__ o_mask, float* __restrict__ o_norm)
{
    __shared__ float4 s_gb[NG];
    __shared__ int s_gl[NG];
    __shared__ float s_gm[NG];
    int b = blockIdx.y;
    for (int i = threadIdx.x; i < NG; i += 256) {
        s_gb[i] = ((const float4*)gboxes)[b * NG + i];
        s_gl[i] = glab[b * NG + i];
        s_gm[i] = gmask[b * NG + i];
    }
    __syncthreads();
    int a = blockIdx.x * 256 + threadIdx.x;
    if (a >= NA) return;
    size_t t = (size_t)b * NA + a;
    unsigned int ew[4];
    ew[0] = bits[t * 4 + 0]; ew[1] = bits[t * 4 + 1];
    ew[2] = bits[t * 4 + 2]; ew[3] = bits[t * 4 + 3];
    int cnt = __popc(ew[0]) + __popc(ew[1]) + __popc(ew[2]) + __popc(ew[3]);
    bool conflict_any = (flagp[0] != 0);
    float best_v = bestvp[t]; int best_g = bestgp[t];
    float4 pb = ((const float4*)pboxes)[t];
    const float* srow = scores + t * NC;

    bool keep = (cnt <= 1);
    float M = 0.0f, mxiou = 0.0f;
    int tgt = 0;
    float fmask = 0.0f;

    if (!conflict_any) {
        fmask = (cnt > 0) ? 1.0f : 0.0f;
        for (int w = 0; w < 4; w++) {
            if (ew[w]) { tgt = w * 32 + __ffs(ew[w]) - 1; break; }
        }
        for (int w = 0; w < 4; w++) {
            unsigned int m = ew[w];
            while (m) {
                int j = __ffs(m) - 1; m &= m - 1;
                int g = w * 32 + j;
                float4 gb = s_gb[g];
                float iv = dev_ciou(pb.x, pb.y, pb.z, pb.w, gb.x, gb.y, gb.z, gb.w);
                float s = srow[s_gl[g]];
                float av = (s * powf(iv, 6.0f)) * s_gm[g];   // bit-identical to k_build
                M = fmaxf(M, av);
                mxiou = fmaxf(mxiou, iv);
            }
        }
    } else if (!keep) {
        fmask = 0.0f; tgt = 0; M = 0.0f; mxiou = 0.0f;   // resolved row all zero
    } else {
        fmask = 1.0f;   // one_hot_best always contributes
        bool eff_best = ((ew[best_g >> 5] >> (best_g & 31)) & 1u) != 0u;
        int first_eff = 1 << 30;
        for (int w = 0; w < 4; w++) {
            if (ew[w]) { first_eff = w * 32 + __ffs(ew[w]) - 1; break; }
        }
        tgt = eff_best ? best_g : (first_eff < best_g ? first_eff : best_g);
        for (int w = 0; w < 4; w++) {
            unsigned int m = ew[w];
            while (m) {
                int j = __ffs(m) - 1; m &= m - 1;
                int g = w * 32 + j;
                float r = (g == best_g) ? 2.0f : 1.0f;
                float4 gb = s_gb[g];
                float iv = dev_ciou(pb.x, pb.y, pb.z, pb.w, gb.x, gb.y, gb.z, gb.w);
                float s = srow[s_gl[g]];
                float av = (s * powf(iv, 6.0f)) * s_gm[g];
                M = fmaxf(M, av * r);
                mxiou = fmaxf(mxiou, iv * r);
            }
        }
        if (!eff_best) {   // one_hot_best adds weight 1 at best_g (iou there counts too)
            float4 gb = s_gb[best_g];
            float iv = dev_ciou(pb.x, pb.y, pb.z, pb.w, gb.x, gb.y, gb.z, gb.w);
            M = fmaxf(M, best_v);
            mxiou = fmaxf(mxiou, iv);
        }
    }

    float norm = (M * M) / (mxiou + 1e-9f);
    int cls = s_gl[tgt];
    float4 gb = s_gb[tgt];
    o_cls[t] = (float)cls;
    ((float4*)o_bbox)[t] = gb;
    o_mask[t] = fmask;
    o_norm[t] = norm;
    // full one-hot score row (replaces the 43 MB memset)
    float* orow = o_scores + t * (size_t)NC;
    #pragma unroll
    for (int j = 0; j < NC / 4; j++) {
        int base = j * 4;
        float4 z;
        z.x = (cls == base + 0) ? norm : 0.0f;
        z.y = (cls == base + 1) ? norm : 0.0f;
        z.z = (cls == base + 2) ? norm : 0.0f;
        z.w = (cls == base + 3) ? norm : 0.0f;
        ((float4*)orow)[j] = z;
    }
}

extern "C" void kernel_launch(void* const* d_in, const int* in_sizes, int n_in,
                              void* d_out, int out_size, void* d_ws, size_t ws_size,
                              hipStream_t stream) {
    const float* pd_scores = (const float*)d_in[0];
    const float* pd_bboxes = (const float*)d_in[1];
    const float* anc       = (const float*)d_in[2];
    const int*   glab      = (const int*)d_in[3];
    const float* gboxes    = (const float*)d_in[4];
    const float* gmask     = (const float*)d_in[5];
    float* out = (float*)d_out;

    char* ws = (char*)d_ws;
    unsigned int* counts = (unsigned int*)(ws + OFF_COUNTS);
    unsigned int* bits   = (unsigned int*)(ws + OFF_BITS);
    unsigned int* selcnt = (unsigned int*)(ws + OFF_SELCNT);
    int*          flag   = (int*)(ws + OFF_FLAG);
    uint2*        pairs  = (uint2*)(ws + OFF_PAIRS);
    float*        bestv  = (float*)(ws + OFF_BESTV);
    int*          bestg  = (int*)(ws + OFF_BESTG);

    hipMemsetAsync(ws, 0, ZERO_END, stream);

    k_build<<<dim3((NA + 63) / 64, BS), 256, 0, stream>>>(
        pd_scores, pd_bboxes, anc, glab, gboxes, gmask, counts, pairs, bestv, bestg);

    k_select<<<dim3(BS * NG / 4), 256, 0, stream>>>(
        counts, pairs, gmask, bits, selcnt, flag);

    k_final<<<dim3((NA + 255) / 256, BS), 256, 0, stream>>>(
        pd_scores, pd_bboxes, glab, gboxes, gmask, bits, flag, bestv, bestg,
        out + OUT_CLS, out + OUT_BBOX, out + OUT_SCORES, out + OUT_MASK, out + OUT_NORM);
}